// Round 8
// baseline (454.801 us; speedup 1.0000x reference)
//
#include <hip/hip_runtime.h>
#include <stdint.h>

typedef short  s16x8 __attribute__((ext_vector_type(8)));
typedef short  s16x4 __attribute__((ext_vector_type(4)));
typedef float  f32x4 __attribute__((ext_vector_type(4)));
typedef unsigned short ushort_t;

#define G_AS __attribute__((address_space(1)))
#define L_AS __attribute__((address_space(3)))

__device__ __forceinline__ void gl_lds16(const void* g, void* l) {
    __builtin_amdgcn_global_load_lds((const G_AS uint32_t*)g, (L_AS uint32_t*)l, 16, 0, 0);
}

__device__ __forceinline__ float b2f(ushort_t u) {
    union { uint32_t i; float f; } v; v.i = ((uint32_t)u) << 16; return v.f;
}
__device__ __forceinline__ ushort_t f2b(float f) {
    uint32_t x = __float_as_uint(f);
    x += 0x7FFF + ((x >> 16) & 1);   // round-to-nearest-even
    return (ushort_t)(x >> 16);
}

#define MFMA16(a, b, c) __builtin_amdgcn_mfma_f32_16x16x32_bf16((a), (b), (c), 0, 0, 0)

// ---------------------------------------------------------------------------
// C: elementwise f32 -> bf16 convert, 8 elems/thread/iter (32B read, 16B write)
// ---------------------------------------------------------------------------
__global__ __launch_bounds__(256) void k_cvt(const float* __restrict__ src,
                                             ushort_t* __restrict__ dst, int n8) {
    int idx = blockIdx.x * 256 + threadIdx.x;
    int stride = gridDim.x * 256;
    for (int i = idx; i < n8; i += stride) {
        f32x4 a = *(const f32x4*)(src + (size_t)i * 8);
        f32x4 b = *(const f32x4*)(src + (size_t)i * 8 + 4);
        s16x8 v;
#pragma unroll
        for (int j = 0; j < 4; ++j) { v[j] = (short)f2b(a[j]); v[j + 4] = (short)f2b(b[j]); }
        *(s16x8*)(dst + (size_t)i * 8) = v;
    }
}

// ---------------------------------------------------------------------------
// P0: transpose+convert up[12][1024][256] f32 -> upT[12][256][1024] bf16
// grid 768 = 12 h * 16 r-tiles * 4 o-tiles, 64x64 tiles, 256 threads
// ---------------------------------------------------------------------------
__global__ __launch_bounds__(256) void k_transpose_up(const float* __restrict__ up,
                                                      ushort_t* __restrict__ upT) {
    int bid = blockIdx.x;
    int h  = bid >> 6;
    int rt = (bid >> 2) & 15;
    int ot = bid & 3;
    int r0 = rt << 6, o0 = ot << 6;
    __shared__ ushort_t tile[64][72];
    int t = threadIdx.x;
    const float* src = up + ((size_t)h << 18) + (size_t)r0 * 256 + o0;
#pragma unroll
    for (int p = 0; p < 2; ++p) {
        int rr = (t >> 3) + (p << 5);
        int cc = (t & 7) << 3;
        f32x4 va = *(const f32x4*)(src + rr * 256 + cc);
        f32x4 vb = *(const f32x4*)(src + rr * 256 + cc + 4);
#pragma unroll
        for (int j = 0; j < 4; ++j) {
            tile[rr][cc + j]     = f2b(va[j]);
            tile[rr][cc + 4 + j] = f2b(vb[j]);
        }
    }
    __syncthreads();
    ushort_t* dst = upT + ((size_t)h << 18) + (size_t)o0 * 1024 + r0;
#pragma unroll
    for (int p = 0; p < 2; ++p) {
        int oo = (t >> 3) + (p << 5);
        int rr = (t & 7) << 3;
        s16x8 v;
#pragma unroll
        for (int j = 0; j < 8; ++j) v[j] = (short)tile[rr + j][oo];
        *(s16x8*)(dst + (size_t)oo * 1024 + rr) = v;
    }
}

// ---------------------------------------------------------------------------
// P1: build WT[3072][3072] bf16, WT[h*256+o][g*256+i] = sum_r down[g,i,r]*mix[g,h,r]*up[h,r,o]
// One block = one (g,h) pair x 128x128 tile of the 256x256 block. grid 576.
// A = downB[g] ([256][1024] bf16), B = upT[h] ([256][1024] bf16), K=1024.
// mix (f32) applied to the B-fragment in-register (per-k scalar).
// ---------------------------------------------------------------------------
__global__ __launch_bounds__(256) void k_build_w(const ushort_t* __restrict__ downB,
                                                 const float* __restrict__ mixp,
                                                 const ushort_t* __restrict__ upT,
                                                 ushort_t* __restrict__ WT) {
    int bid = blockIdx.x;
    int gh = bid >> 2;
    int g = gh / 12, h = gh % 12;
    int it = (bid >> 1) & 1, ot = bid & 1;
    int i0 = it << 7, o0 = ot << 7;

    const ushort_t* A    = downB + ((size_t)g << 18);
    const ushort_t* Bt   = upT   + ((size_t)h << 18);
    const float*    mrow = mixp  + (size_t)(g * 12 + h) * 1024;

    __shared__ ushort_t As[128 * 64];
    __shared__ ushort_t Bs[128 * 64];

    int tid  = threadIdx.x;
    int lane = tid & 63, wave = tid >> 6;
    int wr = wave >> 1, wc = wave & 1;
    int lr = lane & 15;          // row-in-frag for A/B operands
    int kq = (lane >> 4) << 3;   // k-subchunk base (0,8,16,24)

    f32x4 acc[4][4] = {};

    for (int kk = 0; kk < 1024; kk += 64) {
        __syncthreads();
#pragma unroll
        for (int j = 0; j < 4; ++j) {
            int off = (j << 12) + (wave << 10) + (lane << 4);  // byte offset in 16KB
            int row = off >> 7;
            int kc  = (off & 127) >> 1;
            gl_lds16(A  + (size_t)(i0 + row) * 1024 + kk + kc, (char*)As + off);
            gl_lds16(Bt + (size_t)(o0 + row) * 1024 + kk + kc, (char*)Bs + off);
        }
        __syncthreads();
#pragma unroll
        for (int ks = 0; ks < 64; ks += 32) {
            f32x4 m0 = *(const f32x4*)(mrow + kk + ks + kq);
            f32x4 m1 = *(const f32x4*)(mrow + kk + ks + kq + 4);
            float mf[8];
#pragma unroll
            for (int j = 0; j < 4; ++j) { mf[j] = m0[j]; mf[j + 4] = m1[j]; }

            s16x8 bfr[4];
#pragma unroll
            for (int b = 0; b < 4; ++b) {
                s16x8 raw = *(const s16x8*)&Bs[(wc * 64 + b * 16 + lr) * 64 + ks + kq];
#pragma unroll
                for (int j = 0; j < 8; ++j)
                    bfr[b][j] = (short)f2b(b2f((ushort_t)raw[j]) * mf[j]);
            }
            s16x8 afr[4];
#pragma unroll
            for (int a = 0; a < 4; ++a)
                afr[a] = *(const s16x8*)&As[(wr * 64 + a * 16 + lr) * 64 + ks + kq];
#pragma unroll
            for (int a = 0; a < 4; ++a)
#pragma unroll
                for (int b = 0; b < 4; ++b)
                    acc[a][b] = MFMA16(afr[a], bfr[b], acc[a][b]);
        }
    }

    // D[m=i][n=o]; lane: n = lane&15 (+frag), m = (lane>>4)*4 + v (+frag).
    // Write transposed into WT[o-row][i-col]: 4 consecutive i per lane -> 8B store.
    int colbase = g * 256 + i0 + wr * 64;   // i
    int rowbase = h * 256 + o0 + wc * 64;   // o
#pragma unroll
    for (int a = 0; a < 4; ++a)
#pragma unroll
        for (int b = 0; b < 4; ++b) {
            int o = rowbase + b * 16 + lr;
            int i = colbase + a * 16 + ((lane >> 4) << 2);
            s16x4 pv;
#pragma unroll
            for (int v = 0; v < 4; ++v) pv[v] = (short)f2b(acc[a][b][v]);
            *(s16x4*)(WT + (size_t)o * 3072 + i) = pv;
        }
}

// ---------------------------------------------------------------------------
// M: out[8192][3072] f32 = xB[8192][3072] bf16 @ W, W given as WT[n][k] (B^T).
// m97-style: 128x128 tile, BK=64, 4 waves (2x2), 4x4 16x16x32 frags/wave,
// global_load_lds width-16 staging, 2-barrier K-loop. f32 epilogue stores.
// ---------------------------------------------------------------------------
__global__ __launch_bounds__(256) void k_main(const ushort_t* __restrict__ X,
                                              const ushort_t* __restrict__ WT,
                                              float* __restrict__ Y) {
    int bid = blockIdx.x;           // 64 t-tiles * 24 n-tiles
    int nt = bid % 24, tt = bid / 24;
    int t0 = tt << 7, n0 = nt << 7;

    __shared__ ushort_t As[128 * 64];
    __shared__ ushort_t Bs[128 * 64];

    int tid  = threadIdx.x;
    int lane = tid & 63, wave = tid >> 6;
    int wr = wave >> 1, wc = wave & 1;
    int lr = lane & 15;
    int kq = (lane >> 4) << 3;

    f32x4 acc[4][4] = {};

    for (int kk = 0; kk < 3072; kk += 64) {
        __syncthreads();
#pragma unroll
        for (int j = 0; j < 4; ++j) {
            int off = (j << 12) + (wave << 10) + (lane << 4);
            int row = off >> 7;
            int kc  = (off & 127) >> 1;
            gl_lds16(X  + (size_t)(t0 + row) * 3072 + kk + kc, (char*)As + off);
            gl_lds16(WT + (size_t)(n0 + row) * 3072 + kk + kc, (char*)Bs + off);
        }
        __syncthreads();
#pragma unroll
        for (int ks = 0; ks < 64; ks += 32) {
            s16x8 afr[4], bfr[4];
#pragma unroll
            for (int a = 0; a < 4; ++a)
                afr[a] = *(const s16x8*)&As[(wr * 64 + a * 16 + lr) * 64 + ks + kq];
#pragma unroll
            for (int b = 0; b < 4; ++b)
                bfr[b] = *(const s16x8*)&Bs[(wc * 64 + b * 16 + lr) * 64 + ks + kq];
#pragma unroll
            for (int a = 0; a < 4; ++a)
#pragma unroll
                for (int b = 0; b < 4; ++b)
                    acc[a][b] = MFMA16(afr[a], bfr[b], acc[a][b]);
        }
    }

    // D[m=t][n]: n = n0 + wc*64 + b*16 + (lane&15); t = t0 + wr*64 + a*16 + (lane>>4)*4 + v
    int trow = t0 + wr * 64;
    int ncol = n0 + wc * 64;
#pragma unroll
    for (int a = 0; a < 4; ++a)
#pragma unroll
        for (int b = 0; b < 4; ++b) {
            int n  = ncol + b * 16 + lr;
            int tr = trow + a * 16 + ((lane >> 4) << 2);
#pragma unroll
            for (int v = 0; v < 4; ++v)
                Y[(size_t)(tr + v) * 3072 + n] = acc[a][b][v];
        }
}

// ---------------------------------------------------------------------------
extern "C" void kernel_launch(void* const* d_in, const int* in_sizes, int n_in,
                              void* d_out, int out_size, void* d_ws, size_t ws_size,
                              hipStream_t stream) {
    const float* x    = (const float*)d_in[0];   // [8192][3072] f32
    const float* down = (const float*)d_in[1];   // [12][256][1024] f32
    const float* mixp = (const float*)d_in[2];   // [12][12][1024] f32
    const float* up   = (const float*)d_in[3];   // [12][1024][256] f32
    float* out = (float*)d_out;                  // [8192][3072] f32

    // ws layout (ushort elems): WT | upT | downB | xB   (~81.8 MB total)
    ushort_t* WT    = (ushort_t*)d_ws;                     // 3072*3072
    ushort_t* upT   = WT    + (size_t)3072 * 3072;         // 12*256*1024
    ushort_t* downB = upT   + (size_t)12 * 256 * 1024;     // 12*256*1024
    ushort_t* xB    = downB + (size_t)12 * 256 * 1024;     // 8192*3072

    k_cvt         <<<dim3(1536), dim3(256), 0, stream>>>(down, downB, 393216);
    k_transpose_up<<<dim3(768),  dim3(256), 0, stream>>>(up, upT);
    k_build_w     <<<dim3(576),  dim3(256), 0, stream>>>(downB, mixp, upT, WT);
    k_cvt         <<<dim3(2048), dim3(256), 0, stream>>>(x, xB, 3145728);
    k_main        <<<dim3(1536), dim3(256), 0, stream>>>(xB, WT, out);
}

// Round 9
// 410.641 us; speedup vs baseline: 1.1075x; 1.1075x over previous
//
#include <hip/hip_runtime.h>
#include <stdint.h>

typedef short  s16x8 __attribute__((ext_vector_type(8)));
typedef short  s16x4 __attribute__((ext_vector_type(4)));
typedef float  f32x4 __attribute__((ext_vector_type(4)));
typedef unsigned short ushort_t;

#define G_AS __attribute__((address_space(1)))
#define L_AS __attribute__((address_space(3)))

__device__ __forceinline__ void gl_lds16(const void* g, void* l) {
    __builtin_amdgcn_global_load_lds((const G_AS uint32_t*)g, (L_AS uint32_t*)l, 16, 0, 0);
}

__device__ __forceinline__ float b2f(ushort_t u) {
    union { uint32_t i; float f; } v; v.i = ((uint32_t)u) << 16; return v.f;
}
__device__ __forceinline__ ushort_t f2b(float f) {
    uint32_t x = __float_as_uint(f);
    x += 0x7FFF + ((x >> 16) & 1);   // round-to-nearest-even
    return (ushort_t)(x >> 16);
}

#define MFMA16(a, b, c) __builtin_amdgcn_mfma_f32_16x16x32_bf16((a), (b), (c), 0, 0, 0)

// ---------------------------------------------------------------------------
// C: elementwise f32 -> bf16 convert, 8 elems/thread/iter
// ---------------------------------------------------------------------------
__global__ __launch_bounds__(256) void k_cvt(const float* __restrict__ src,
                                             ushort_t* __restrict__ dst, int n8) {
    int idx = blockIdx.x * 256 + threadIdx.x;
    int stride = gridDim.x * 256;
    for (int i = idx; i < n8; i += stride) {
        f32x4 a = *(const f32x4*)(src + (size_t)i * 8);
        f32x4 b = *(const f32x4*)(src + (size_t)i * 8 + 4);
        s16x8 v;
#pragma unroll
        for (int j = 0; j < 4; ++j) { v[j] = (short)f2b(a[j]); v[j + 4] = (short)f2b(b[j]); }
        *(s16x8*)(dst + (size_t)i * 8) = v;
    }
}

// ---------------------------------------------------------------------------
// P0: transpose+convert up[12][1024][256] f32 -> upT[12][256][1024] bf16
// ---------------------------------------------------------------------------
__global__ __launch_bounds__(256) void k_transpose_up(const float* __restrict__ up,
                                                      ushort_t* __restrict__ upT) {
    int bid = blockIdx.x;
    int h  = bid >> 6;
    int rt = (bid >> 2) & 15;
    int ot = bid & 3;
    int r0 = rt << 6, o0 = ot << 6;
    __shared__ ushort_t tile[64][72];
    int t = threadIdx.x;
    const float* src = up + ((size_t)h << 18) + (size_t)r0 * 256 + o0;
#pragma unroll
    for (int p = 0; p < 2; ++p) {
        int rr = (t >> 3) + (p << 5);
        int cc = (t & 7) << 3;
        f32x4 va = *(const f32x4*)(src + rr * 256 + cc);
        f32x4 vb = *(const f32x4*)(src + rr * 256 + cc + 4);
#pragma unroll
        for (int j = 0; j < 4; ++j) {
            tile[rr][cc + j]     = f2b(va[j]);
            tile[rr][cc + 4 + j] = f2b(vb[j]);
        }
    }
    __syncthreads();
    ushort_t* dst = upT + ((size_t)h << 18) + (size_t)o0 * 1024 + r0;
#pragma unroll
    for (int p = 0; p < 2; ++p) {
        int oo = (t >> 3) + (p << 5);
        int rr = (t & 7) << 3;
        s16x8 v;
#pragma unroll
        for (int j = 0; j < 8; ++j) v[j] = (short)tile[rr + j][oo];
        *(s16x8*)(dst + (size_t)oo * 1024 + rr) = v;
    }
}

// ---------------------------------------------------------------------------
// P1: build WT[3072][3072] bf16 (unchanged from R8 verified version)
// ---------------------------------------------------------------------------
__global__ __launch_bounds__(256) void k_build_w(const ushort_t* __restrict__ downB,
                                                 const float* __restrict__ mixp,
                                                 const ushort_t* __restrict__ upT,
                                                 ushort_t* __restrict__ WT) {
    int bid = blockIdx.x;
    int gh = bid >> 2;
    int g = gh / 12, h = gh % 12;
    int it = (bid >> 1) & 1, ot = bid & 1;
    int i0 = it << 7, o0 = ot << 7;

    const ushort_t* A    = downB + ((size_t)g << 18);
    const ushort_t* Bt   = upT   + ((size_t)h << 18);
    const float*    mrow = mixp  + (size_t)(g * 12 + h) * 1024;

    __shared__ ushort_t As[128 * 64];
    __shared__ ushort_t Bs[128 * 64];

    int tid  = threadIdx.x;
    int lane = tid & 63, wave = tid >> 6;
    int wr = wave >> 1, wc = wave & 1;
    int lr = lane & 15;
    int kq = (lane >> 4) << 3;

    f32x4 acc[4][4] = {};

    for (int kk = 0; kk < 1024; kk += 64) {
        __syncthreads();
#pragma unroll
        for (int j = 0; j < 4; ++j) {
            int off = (j << 12) + (wave << 10) + (lane << 4);
            int row = off >> 7;
            int kc  = (off & 127) >> 1;
            gl_lds16(A  + (size_t)(i0 + row) * 1024 + kk + kc, (char*)As + off);
            gl_lds16(Bt + (size_t)(o0 + row) * 1024 + kk + kc, (char*)Bs + off);
        }
        __syncthreads();
#pragma unroll
        for (int ks = 0; ks < 64; ks += 32) {
            f32x4 m0 = *(const f32x4*)(mrow + kk + ks + kq);
            f32x4 m1 = *(const f32x4*)(mrow + kk + ks + kq + 4);
            float mf[8];
#pragma unroll
            for (int j = 0; j < 4; ++j) { mf[j] = m0[j]; mf[j + 4] = m1[j]; }

            s16x8 bfr[4];
#pragma unroll
            for (int b = 0; b < 4; ++b) {
                s16x8 raw = *(const s16x8*)&Bs[(wc * 64 + b * 16 + lr) * 64 + ks + kq];
#pragma unroll
                for (int j = 0; j < 8; ++j)
                    bfr[b][j] = (short)f2b(b2f((ushort_t)raw[j]) * mf[j]);
            }
            s16x8 afr[4];
#pragma unroll
            for (int a = 0; a < 4; ++a)
                afr[a] = *(const s16x8*)&As[(wr * 64 + a * 16 + lr) * 64 + ks + kq];
#pragma unroll
            for (int a = 0; a < 4; ++a)
#pragma unroll
                for (int b = 0; b < 4; ++b)
                    acc[a][b] = MFMA16(afr[a], bfr[b], acc[a][b]);
        }
    }

    int colbase = g * 256 + i0 + wr * 64;
    int rowbase = h * 256 + o0 + wc * 64;
#pragma unroll
    for (int a = 0; a < 4; ++a)
#pragma unroll
        for (int b = 0; b < 4; ++b) {
            int o = rowbase + b * 16 + lr;
            int i = colbase + a * 16 + ((lane >> 4) << 2);
            s16x4 pv;
#pragma unroll
            for (int v = 0; v < 4; ++v) pv[v] = (short)f2b(acc[a][b][v]);
            *(s16x4*)(WT + (size_t)o * 3072 + i) = pv;
        }
}

// ---------------------------------------------------------------------------
// M: 256x256-tile 8-phase GEMM (m201 template port).
// out[8192][3072] f32 = xB bf16 @ W (WT[n][k] B^T form).
// 512 thr = 8 waves (2M x 4N), per-wave 128x64. BK=64 as two 32-k halves.
// LDS 128KB dynamic: [buf2][op2][khalf2][256*32] bf16, chunk-XOR swizzled.
// Per tile: 4 phases {ds_read quadrant | stage 1 half -> s_barrier ->
// lgkmcnt(0) -> setprio(1) 16xMFMA setprio(0) [-> vmcnt(4)] -> s_barrier}.
// Counted vmcnt(4) at phase 1/3 ends; epilogue tile drains 4->0.
// ---------------------------------------------------------------------------
#define BAR() __builtin_amdgcn_s_barrier()
#define WAITV(n) asm volatile("s_waitcnt vmcnt(" #n ")" ::: "memory")
#define WAITL() asm volatile("s_waitcnt lgkmcnt(0)" ::: "memory")

__global__ __launch_bounds__(512, 1) void k_main8(const ushort_t* __restrict__ X,
                                                  const ushort_t* __restrict__ WT,
                                                  float* __restrict__ Y) {
    extern __shared__ ushort_t lds[];   // [buf][op][kh][8192]  = 128 KiB
    int bid = blockIdx.x;               // 384 = 8 XCD * 48
    int wg  = (bid & 7) * 48 + (bid >> 3);
    int tt = wg / 12, nt = wg % 12;
    int m0 = tt << 8, n0 = nt << 8;

    int tid  = threadIdx.x;
    int lane = tid & 63;
    int wave = tid >> 6;
    int wr = wave >> 2;          // 0..1
    int wc = wave & 3;           // 0..3
    int lr = lane & 15;
    int cq = lane >> 4;          // k-chunk 0..3

    // stage one 16KB half (256 rows x 32 k): 2 x gl_lds16 per thread.
    // LDS linear; global source pre-swizzled (chunk ^= (row>>1)&3).
    auto STAGE = [&](int buf, int op, int kh, int t) {
        const ushort_t* src = op ? WT : X;
        int rb = op ? n0 : m0;
        int kb = t * 64 + kh * 32;
        ushort_t* base = lds + buf * 32768 + op * 16384 + kh * 8192;
#pragma unroll
        for (int j = 0; j < 2; ++j) {
            int boff = (j << 13) + (tid << 4);      // byte offset in half
            int r  = boff >> 6;
            int ch = (boff >> 4) & 3;
            int ks = kb + ((ch ^ ((r >> 1) & 3)) << 3);
            gl_lds16(src + (size_t)(rb + r) * 3072 + ks, (char*)base + boff);
        }
    };
    // read one 16x8 fragment (swizzled)
    auto RD = [&](int buf, int op, int kh, int fr) -> s16x8 {
        int row = (op ? wc * 64 : wr * 128) + fr * 16 + lr;
        int off = buf * 32768 + op * 16384 + kh * 8192 + row * 32
                + ((cq ^ ((row >> 1) & 3)) << 3);
        return *(const s16x8*)(lds + off);
    };

    f32x4 acc[8][4] = {};
    s16x8 af[4], bf[4];

#define PH_READ_AB(mlo, kh) { _Pragma("unroll") for (int i = 0; i < 4; ++i) af[i] = RD(cur, 0, kh, (mlo) + i); \
                              _Pragma("unroll") for (int i = 0; i < 4; ++i) bf[i] = RD(cur, 1, kh, i); }
#define PH_READ_A(mlo, kh)  { _Pragma("unroll") for (int i = 0; i < 4; ++i) af[i] = RD(cur, 0, kh, (mlo) + i); }
#define PH_MFMA(mlo)        { __builtin_amdgcn_s_setprio(1); \
                              _Pragma("unroll") for (int mi = 0; mi < 4; ++mi) \
                              _Pragma("unroll") for (int ni = 0; ni < 4; ++ni) \
                                  acc[(mlo) + mi][ni] = MFMA16(af[mi], bf[ni], acc[(mlo) + mi][ni]); \
                              __builtin_amdgcn_s_setprio(0); }

    // prologue: stage all 4 halves of tile 0 into buf 0
    STAGE(0, 0, 0, 0); STAGE(0, 1, 0, 0); STAGE(0, 0, 1, 0); STAGE(0, 1, 1, 0);
    WAITV(4); BAR();

    int cur = 0;
    for (int t = 0; t < 47; ++t) {
        int nx = cur ^ 1;
        // ph0: quadrant m0-3 x k0
        PH_READ_AB(0, 0); STAGE(nx, 0, 0, t + 1);
        BAR(); WAITL(); PH_MFMA(0); BAR();
        // ph1: m4-7 x k0 (reuse bf)
        PH_READ_A(4, 0);  STAGE(nx, 1, 0, t + 1);
        BAR(); WAITL(); PH_MFMA(4); WAITV(4); BAR();
        // ph2: m0-3 x k1
        PH_READ_AB(0, 1); STAGE(nx, 0, 1, t + 1);
        BAR(); WAITL(); PH_MFMA(0); BAR();
        // ph3: m4-7 x k1
        PH_READ_A(4, 1);  STAGE(nx, 1, 1, t + 1);
        BAR(); WAITL(); PH_MFMA(4); WAITV(4); BAR();
        cur = nx;
    }
    // last tile (t = 47): no staging; drain 4 -> 0
    PH_READ_AB(0, 0); BAR(); WAITL(); PH_MFMA(0); BAR();
    PH_READ_A(4, 0);  BAR(); WAITL(); PH_MFMA(4); WAITV(0); BAR();
    PH_READ_AB(0, 1); BAR(); WAITL(); PH_MFMA(0); BAR();
    PH_READ_A(4, 1);  BAR(); WAITL(); PH_MFMA(4);

    // epilogue: D[m][n] f32; row = m0+wr*128+mi*16+cq*4+v, col = n0+wc*64+ni*16+lr
    int trow = m0 + wr * 128 + (cq << 2);
    int ncol = n0 + wc * 64 + lr;
#pragma unroll
    for (int mi = 0; mi < 8; ++mi)
#pragma unroll
        for (int ni = 0; ni < 4; ++ni) {
            int rr = trow + mi * 16;
            int cc = ncol + ni * 16;
#pragma unroll
            for (int v = 0; v < 4; ++v)
                Y[(size_t)(rr + v) * 3072 + cc] = acc[mi][ni][v];
        }
}

// ---------------------------------------------------------------------------
extern "C" void kernel_launch(void* const* d_in, const int* in_sizes, int n_in,
                              void* d_out, int out_size, void* d_ws, size_t ws_size,
                              hipStream_t stream) {
    const float* x    = (const float*)d_in[0];   // [8192][3072] f32
    const float* down = (const float*)d_in[1];   // [12][256][1024] f32
    const float* mixp = (const float*)d_in[2];   // [12][12][1024] f32
    const float* up   = (const float*)d_in[3];   // [12][1024][256] f32
    float* out = (float*)d_out;                  // [8192][3072] f32

    ushort_t* WT    = (ushort_t*)d_ws;                     // 3072*3072
    ushort_t* upT   = WT    + (size_t)3072 * 3072;         // 12*256*1024
    ushort_t* downB = upT   + (size_t)12 * 256 * 1024;     // 12*256*1024
    ushort_t* xB    = downB + (size_t)12 * 256 * 1024;     // 8192*3072

    static int lds_attr_set = 0;
    if (!lds_attr_set) {
        hipFuncSetAttribute((const void*)k_main8,
                            hipFuncAttributeMaxDynamicSharedMemorySize, 131072);
        lds_attr_set = 1;
    }

    k_cvt         <<<dim3(1536), dim3(256), 0, stream>>>(down, downB, 393216);
    k_transpose_up<<<dim3(768),  dim3(256), 0, stream>>>(up, upT);
    k_build_w     <<<dim3(576),  dim3(256), 0, stream>>>(downB, mixp, upT, WT);
    k_cvt         <<<dim3(2048), dim3(256), 0, stream>>>(x, xB, 3145728);
    k_main8       <<<dim3(384),  dim3(512), 131072, stream>>>(xB, WT, out);
}